// Round 11
// baseline (365.329 us; speedup 1.0000x reference)
//
#include <hip/hip_runtime.h>
#include <cstdint>
#include <cstddef>

typedef __bf16 bf16x8 __attribute__((ext_vector_type(8)));
typedef __bf16 bf16x2 __attribute__((ext_vector_type(2)));
typedef float f32x4 __attribute__((ext_vector_type(4)));

#define L_SEQ 32768
#define H_DIM 512
#define P_DIM 256
#define NP2   512      // 2P = K and N of both GEMMs
#define CHUNK 32
#define NCHUNK 1024    // L / CHUNK

__device__ __forceinline__ void gload_lds16(const void* g, void* l) {
    __builtin_amdgcn_global_load_lds(
        (const __attribute__((address_space(1))) void*)g,
        (__attribute__((address_space(3))) void*)l,
        16, 0, 0);
}

// ---------------- fused setup: prep (block 0) | build B/C (blocks 1..1024) |
// cast u->bf16 (blocks 1025..9216). Builders recompute coef inline (p uniform
// per block -> scalar transcendentals, free).
// par layout (floats): [0]=Ar [256]=Ai [1024]=PowR(Lbar^32) [1280]=PowI
__global__ void setup_kernel(const float* __restrict__ Lre, const float* __restrict__ Lim,
                             const float* __restrict__ lstep,
                             const float* __restrict__ Bre, const float* __restrict__ Bim,
                             const float* __restrict__ Cre, const float* __restrict__ Cim,
                             const float4* __restrict__ uin,
                             float* __restrict__ par,
                             __bf16* __restrict__ Bt, __bf16* __restrict__ Ct,
                             bf16x8* __restrict__ Ubf) {
    int b = blockIdx.x;
    if (b == 0) {
        int p = threadIdx.x;
        float lr = fminf(Lre[p], -1e-4f);       // clip_eigs
        float li = Lim[p];
        float st = expf(lstep[p]);
        float ldr = lr * st;
        float ldi = li * st;
        float er = expf(ldr);
        par[p]        = er * cosf(ldi);         // Ar
        par[256 + p]  = er * sinf(ldi);         // Ai
        float e32  = expf((float)CHUNK * ldr);
        float ph32 = (float)CHUNK * ldi;
        par[1024 + p] = e32 * cosf(ph32);       // PowR = Re(Lbar^32)
        par[1280 + p] = e32 * sinf(ph32);       // PowI
    } else if (b <= 1024) {
        int bb = b - 1;
        if (bb < 512) {
            int idx = bb * 256 + threadIdx.x;   // [0, P*H)
            int p = idx >> 9;                   // uniform per block
            float lr = fminf(Lre[p], -1e-4f);
            float li = Lim[p];
            float st = expf(lstep[p]);
            float er = expf(lr * st);
            float ar = er * cosf(li * st);
            float ai = er * sinf(li * st);
            float den = lr * lr + li * li;
            float mr = ar - 1.0f, mi = ai;
            float cr = (mr * lr + mi * li) / den;   // coef = (Lbar-1)/Lambda
            float ci = (mi * lr - mr * li) / den;
            float br = Bre[idx], bi = Bim[idx];
            int h = idx & 511;
            Bt[(size_t)p * NP2 + h]         = (__bf16)(cr * br - ci * bi);
            Bt[(size_t)(256 + p) * NP2 + h] = (__bf16)(cr * bi + ci * br);
        } else {
            int idx = (bb - 512) * 256 + threadIdx.x;   // [0, H*P)
            int h = idx >> 8;
            int q = idx & 255;
            Ct[(size_t)h * NP2 + q]       = (__bf16)( 2.0f * Cre[idx]);
            Ct[(size_t)h * NP2 + 256 + q] = (__bf16)(-2.0f * Cim[idx]);
        }
    } else {
        int i = (b - 1025) * 256 + threadIdx.x;     // [0, L*H/8)
        float4 a = uin[2 * i], c = uin[2 * i + 1];
        bf16x8 v;
        v[0] = (__bf16)a.x; v[1] = (__bf16)a.y; v[2] = (__bf16)a.z; v[3] = (__bf16)a.w;
        v[4] = (__bf16)c.x; v[5] = (__bf16)c.y; v[6] = (__bf16)c.z; v[7] = (__bf16)c.w;
        Ubf[i] = v;
    }
}

// ---------------- GEMM: A(M,512) bf16 x Bt(512,512) bf16 (N,K), 128x128 tile, BK=64 ----------------
// R8-validated core. A: 3 buffers (2 ahead); B: 2 buffers (1 ahead, L2-resident).
// Shared pool 80KB (2 blocks/CU), aliased by the epilogue staging (67.6KB).
// vmcnt ledger (4 loads/unit; per-iter issue B(t+1), A(t+2)): steady queue at
// wait = [A(t),B(t),A(t+1),B(t+1),A(t+2)] = 20 -> vmcnt(12) drains A(t)+B(t).
// ks=6 -> vmcnt(8); ks=7 -> vmcnt(0). Overwrites fenced by trailing barrier.
// Full 8-slot XOR source-side swizzle (rule #21) + swizzled reads (conflicts=0).
// Epilogue: stage acc f32 -> LDS (stride 132 = conflict-free pad), then each
// thread streams one 64-col row-half: float4 stores, bf16x8 Ubf, float4 Dvec.
// FUSE=false: out bf16 (Bu). FUSE=true: out f32 = acc + D[col]*Ubf[o].
template<bool FUSE>
__global__ __launch_bounds__(256)
void gemm_bt_kernel(const __bf16* __restrict__ A, const __bf16* __restrict__ Bt,
                    void* __restrict__ CoutV, const float* __restrict__ Dvec,
                    const __bf16* __restrict__ Ubf) {
    const int K = NP2, N = NP2;
    __shared__ __align__(16) char pool[81920];          // 48KB As[3] + 32KB Bs[2]
    __bf16* Asp = (__bf16*)pool;                        // 3 x 8192 elems
    __bf16* Bsp = (__bf16*)(pool + 49152);              // 2 x 8192 elems
    const int t = threadIdx.x;
    const int l = t & 63;
    const int w = t >> 6;
    const int wr = w >> 1, wc = w & 1;
    // XCD-aware bijective remap: 1024 blocks = 8 XCDs * 128 slots
    const int b    = blockIdx.x;
    const int n_sw = (b & 7) * 128 + (b >> 3);
    const int row0 = (n_sw >> 2) * 128;
    const int col0 = (n_sw & 3) * 128;
    const int lr = l & 15;
    const int lk = (l >> 4) * 8;
    f32x4 acc[4][4] = {};

    auto STAGE_A = [&](int buf, int k0) {
#pragma unroll
        for (int i = 0; i < 4; ++i) {
            int off = i * 256 + t;
            int r  = off >> 3;
            int ce = ((off & 7) ^ (r & 7)) * 8;
            gload_lds16(A + (size_t)(row0 + r) * K + (k0 + ce), Asp + buf * 8192 + off * 8);
        }
    };
    auto STAGE_B = [&](int buf, int k0) {
#pragma unroll
        for (int i = 0; i < 4; ++i) {
            int off = i * 256 + t;
            int r  = off >> 3;
            int ce = ((off & 7) ^ (r & 7)) * 8;
            gload_lds16(Bt + (size_t)(col0 + r) * K + (k0 + ce), Bsp + buf * 8192 + off * 8);
        }
    };

    auto COMPUTE = [&](int ba, int bb) {
#pragma unroll
        for (int kk = 0; kk < 64; kk += 32) {
            bf16x8 a[4], b2[4];
            const int ls = (kk + lk) >> 3;
#pragma unroll
            for (int m = 0; m < 4; ++m) {
                int row = wr * 64 + m * 16 + lr;
                a[m] = *reinterpret_cast<const bf16x8*>(Asp + ba * 8192 + row * 64 + ((ls ^ (row & 7)) << 3));
            }
#pragma unroll
            for (int n = 0; n < 4; ++n) {
                int row = wc * 64 + n * 16 + lr;
                b2[n] = *reinterpret_cast<const bf16x8*>(Bsp + bb * 8192 + row * 64 + ((ls ^ (row & 7)) << 3));
            }
            __builtin_amdgcn_s_setprio(1);
#pragma unroll
            for (int m = 0; m < 4; ++m)
#pragma unroll
                for (int n = 0; n < 4; ++n)
                    acc[m][n] = __builtin_amdgcn_mfma_f32_16x16x32_bf16(a[m], b2[n], acc[m][n], 0, 0, 0);
            __builtin_amdgcn_s_setprio(0);
        }
    };

    // prologue: A0, B0, A1  (queue = 12)
    STAGE_A(0, 0);
    STAGE_B(0, 0);
    STAGE_A(1, 64);
#pragma unroll
    for (int ks = 0; ks < 8; ++ks) {
        if (ks + 1 < 8) STAGE_B((ks + 1) & 1, (ks + 1) * 64);
        if (ks + 2 < 8) STAGE_A((ks + 2) % 3, (ks + 2) * 64);
        if (ks <= 5)      { asm volatile("s_waitcnt vmcnt(12)" ::: "memory"); }
        else if (ks == 6) { asm volatile("s_waitcnt vmcnt(8)"  ::: "memory"); }
        else              { asm volatile("s_waitcnt vmcnt(0)"  ::: "memory"); }
        __builtin_amdgcn_s_barrier();           // A(ks),B(ks) staged by ALL waves
        __builtin_amdgcn_sched_barrier(0);
        COMPUTE(ks % 3, ks & 1);
        __builtin_amdgcn_sched_barrier(0);
        __builtin_amdgcn_s_barrier();           // all waves done reading bufs of tile ks
    }

    // ---- epilogue: LDS-staged coalesced writes (aliases As/Bs; safe after
    // the trailing barrier above) ----
    float* st = (float*)pool;                   // 128 rows x stride 132 f32
    const int lg = (l >> 4) * 4;
#pragma unroll
    for (int m = 0; m < 4; ++m)
#pragma unroll
        for (int n = 0; n < 4; ++n)
#pragma unroll
            for (int j = 0; j < 4; ++j)
                st[(wr * 64 + m * 16 + lg + j) * 132 + (wc * 64 + n * 16 + lr)] = acc[m][n][j];
    __syncthreads();

    const int row  = t >> 1;
    const int half = t & 1;
    const float* srow = st + row * 132 + half * 64;
    const size_t gbase = (size_t)(row0 + row) * N + col0 + half * 64;
    if (FUSE) {
        float* out = (float*)CoutV;
        const float* dv = Dvec + col0 + half * 64;
#pragma unroll
        for (int c = 0; c < 8; ++c) {
            float4 v0 = *(const float4*)(srow + c * 8);
            float4 v1 = *(const float4*)(srow + c * 8 + 4);
            bf16x8 uv = *reinterpret_cast<const bf16x8*>(Ubf + gbase + c * 8);
            float4 d0 = *(const float4*)(dv + c * 8);
            float4 d1 = *(const float4*)(dv + c * 8 + 4);
            float4 o0, o1;
            o0.x = fmaf(d0.x, (float)uv[0], v0.x);
            o0.y = fmaf(d0.y, (float)uv[1], v0.y);
            o0.z = fmaf(d0.z, (float)uv[2], v0.z);
            o0.w = fmaf(d0.w, (float)uv[3], v0.w);
            o1.x = fmaf(d1.x, (float)uv[4], v1.x);
            o1.y = fmaf(d1.y, (float)uv[5], v1.y);
            o1.z = fmaf(d1.z, (float)uv[6], v1.z);
            o1.w = fmaf(d1.w, (float)uv[7], v1.w);
            *(float4*)(out + gbase + c * 8)     = o0;
            *(float4*)(out + gbase + c * 8 + 4) = o1;
        }
    } else {
        __bf16* out = (__bf16*)CoutV;
#pragma unroll
        for (int c = 0; c < 8; ++c) {
            float4 v0 = *(const float4*)(srow + c * 8);
            float4 v1 = *(const float4*)(srow + c * 8 + 4);
            bf16x8 v;
            v[0] = (__bf16)v0.x; v[1] = (__bf16)v0.y; v[2] = (__bf16)v0.z; v[3] = (__bf16)v0.w;
            v[4] = (__bf16)v1.x; v[5] = (__bf16)v1.y; v[6] = (__bf16)v1.z; v[7] = (__bf16)v1.w;
            *reinterpret_cast<bf16x8*>(out + gbase + c * 8) = v;
        }
    }
}

// ---------------- chunked scan (Bu bf16; 128 threads, 2 channels/thread) ----------------
// Level 0: per-chunk totals. Fc[g*128+t] = (xr0, xi0, xr1, xi1) for channels 2t, 2t+1.
__global__ void scanA_kernel(const __bf16* __restrict__ Bu, const float* __restrict__ par,
                             float4* __restrict__ Fc) {
    int g = blockIdx.x;
    int t = threadIdx.x;                // 0..127
    int p0 = 2 * t, p1 = 2 * t + 1;
    float ar0 = par[p0], ai0 = par[256 + p0];
    float ar1 = par[p1], ai1 = par[256 + p1];
    const __bf16* bu = Bu + (size_t)g * CHUNK * NP2;
    float xr0 = 0.f, xi0 = 0.f, xr1 = 0.f, xi1 = 0.f;
#pragma unroll 4
    for (int i = 0; i < CHUNK; ++i) {
        bf16x2 re = *reinterpret_cast<const bf16x2*>(bu + i * NP2 + p0);
        bf16x2 im = *reinterpret_cast<const bf16x2*>(bu + i * NP2 + 256 + p0);
        float br0 = (float)re[0], br1 = (float)re[1];
        float bi0 = (float)im[0], bi1 = (float)im[1];
        float nr0 = fmaf(ar0, xr0, fmaf(-ai0, xi0, br0));
        float ni0 = fmaf(ar0, xi0, fmaf( ai0, xr0, bi0));
        float nr1 = fmaf(ar1, xr1, fmaf(-ai1, xi1, br1));
        float ni1 = fmaf(ar1, xi1, fmaf( ai1, xr1, bi1));
        xr0 = nr0; xi0 = ni0; xr1 = nr1; xi1 = ni1;
    }
    float4 f; f.x = xr0; f.y = xi0; f.z = xr1; f.w = xi1;
    Fc[g * 128 + t] = f;
}

// Final: carry = deterministic serial chain e = Lbar^32 * e + F[j] over j<g
// (replaces scanB1 + hierarchy; worst block 1023*~8cy ~ 3.4us, hidden under
// other blocks' HBM streaming), then 32-row replay writing xs (bf16).
__global__ void scanC_kernel(const __bf16* __restrict__ Bu, const float* __restrict__ par,
                             const float4* __restrict__ Fc, __bf16* __restrict__ xs) {
    int g = blockIdx.x;
    int t = threadIdx.x;                // 0..127
    int p0 = 2 * t, p1 = 2 * t + 1;
    float ar0 = par[p0], ai0 = par[256 + p0];
    float ar1 = par[p1], ai1 = par[256 + p1];
    float pr0 = par[1024 + p0], pi0 = par[1280 + p0];   // Lbar^32
    float pr1 = par[1024 + p1], pi1 = par[1280 + p1];
    float er0 = 0.f, ei0 = 0.f, er1 = 0.f, ei1 = 0.f;
    for (int j = 0; j < g; ++j) {
        float4 f = Fc[j * 128 + t];
        float nr0 = fmaf(pr0, er0, fmaf(-pi0, ei0, f.x));
        float ni0 = fmaf(pr0, ei0, fmaf( pi0, er0, f.y));
        float nr1 = fmaf(pr1, er1, fmaf(-pi1, ei1, f.z));
        float ni1 = fmaf(pr1, ei1, fmaf( pi1, er1, f.w));
        er0 = nr0; ei0 = ni0; er1 = nr1; ei1 = ni1;
    }
    float xr0 = er0, xi0 = ei0, xr1 = er1, xi1 = ei1;
    const __bf16* bu = Bu + (size_t)g * CHUNK * NP2;
    __bf16* xo = xs + (size_t)g * CHUNK * NP2;
#pragma unroll 4
    for (int i = 0; i < CHUNK; ++i) {
        bf16x2 re = *reinterpret_cast<const bf16x2*>(bu + i * NP2 + p0);
        bf16x2 im = *reinterpret_cast<const bf16x2*>(bu + i * NP2 + 256 + p0);
        float nr0 = fmaf(ar0, xr0, fmaf(-ai0, xi0, (float)re[0]));
        float ni0 = fmaf(ar0, xi0, fmaf( ai0, xr0, (float)im[0]));
        float nr1 = fmaf(ar1, xr1, fmaf(-ai1, xi1, (float)re[1]));
        float ni1 = fmaf(ar1, xi1, fmaf( ai1, xr1, (float)im[1]));
        xr0 = nr0; xi0 = ni0; xr1 = nr1; xi1 = ni1;
        bf16x2 wre; wre[0] = (__bf16)xr0; wre[1] = (__bf16)xr1;
        bf16x2 wim; wim[0] = (__bf16)xi0; wim[1] = (__bf16)xi1;
        *reinterpret_cast<bf16x2*>(xo + i * NP2 + p0)       = wre;
        *reinterpret_cast<bf16x2*>(xo + i * NP2 + 256 + p0) = wim;
    }
}

extern "C" void kernel_launch(void* const* d_in, const int* in_sizes, int n_in,
                              void* d_out, int out_size, void* d_ws, size_t ws_size,
                              hipStream_t stream) {
    const float* u   = (const float*)d_in[0];
    const float* Lre = (const float*)d_in[1];
    const float* Lim = (const float*)d_in[2];
    const float* Bre = (const float*)d_in[3];
    const float* Bim = (const float*)d_in[4];
    const float* Cre = (const float*)d_in[5];
    const float* Cim = (const float*)d_in[6];
    const float* Dv  = (const float*)d_in[7];
    const float* lst = (const float*)d_in[8];

    char* w = (char*)d_ws;
    size_t off = 0;
    float* par = (float*)(w + off);      off += 16 * 1024;
    __bf16* Btm = (__bf16*)(w + off);    off += (size_t)NP2 * NP2 * 2;      // 512 KB
    __bf16* Ctm = (__bf16*)(w + off);    off += (size_t)NP2 * NP2 * 2;      // 512 KB
    float4* Fc = (float4*)(w + off);     off += (size_t)NCHUNK * 128 * 16;  // 2 MB
    __bf16* Ubf = (__bf16*)(w + off);    off += (size_t)L_SEQ * H_DIM * 2;  // 32 MB (bf16 u)
    __bf16* Xs  = (__bf16*)(w + off);    off += (size_t)L_SEQ * NP2 * 2;    // 32 MB (xs)
    if (ws_size < off) return;  // fail loudly (output stays poisoned)

    // Bu: bf16 L x 2P (32 MB) in the lower half of d_out; GEMM2 overwrites
    // all of d_out (f32 output) afterwards.
    __bf16* Bu = (__bf16*)d_out;

    setup_kernel  <<<9217, 256, 0, stream>>>(Lre, Lim, lst, Bre, Bim, Cre, Cim,
                                             (const float4*)u, par, Btm, Ctm, (bf16x8*)Ubf);
    gemm_bt_kernel<false><<<1024, 256, 0, stream>>>(Ubf, Btm, (void*)Bu, nullptr, nullptr);
    scanA_kernel  <<<NCHUNK, 128, 0, stream>>>(Bu, par, Fc);
    scanC_kernel  <<<NCHUNK, 128, 0, stream>>>(Bu, par, Fc, Xs);
    gemm_bt_kernel<true><<<1024, 256, 0, stream>>>(Xs, Ctm, d_out, Dv, Ubf);
}

// Round 12
// 122.380 us; speedup vs baseline: 2.9852x; 2.9852x over previous
//
#include <hip/hip_runtime.h>
#include <cstdint>
#include <cstddef>

typedef __bf16 bf16x8 __attribute__((ext_vector_type(8)));
typedef __bf16 bf16x2 __attribute__((ext_vector_type(2)));
typedef float f32x4 __attribute__((ext_vector_type(4)));

#define L_SEQ 32768
#define H_DIM 512
#define P_DIM 256
#define NP2   512      // 2P = K and N of both GEMMs
#define CHUNK 32
#define NCHUNK 1024    // L / CHUNK
#define NSUPER 32      // NCHUNK / 32

__device__ __forceinline__ void gload_lds16(const void* g, void* l) {
    __builtin_amdgcn_global_load_lds(
        (const __attribute__((address_space(1))) void*)g,
        (__attribute__((address_space(3))) void*)l,
        16, 0, 0);
}

// ---------------- fused setup: prep (block 0) | build B/C (blocks 1..1024) |
// cast u->bf16 (blocks 1025..9216). Builders recompute coef inline (p uniform
// per block -> scalar transcendentals, free).
// par layout (floats): [0]=Ar [256]=Ai [1024]=PowR(Lbar^32) [1280]=PowI
//                      [1536]=ldr [1792]=ldi
__global__ void setup_kernel(const float* __restrict__ Lre, const float* __restrict__ Lim,
                             const float* __restrict__ lstep,
                             const float* __restrict__ Bre, const float* __restrict__ Bim,
                             const float* __restrict__ Cre, const float* __restrict__ Cim,
                             const float4* __restrict__ uin,
                             float* __restrict__ par,
                             __bf16* __restrict__ Bt, __bf16* __restrict__ Ct,
                             bf16x8* __restrict__ Ubf) {
    int b = blockIdx.x;
    if (b == 0) {
        int p = threadIdx.x;
        float lr = fminf(Lre[p], -1e-4f);       // clip_eigs
        float li = Lim[p];
        float st = expf(lstep[p]);
        float ldr = lr * st;
        float ldi = li * st;
        float er = expf(ldr);
        par[p]        = er * cosf(ldi);         // Ar
        par[256 + p]  = er * sinf(ldi);         // Ai
        float e32  = expf((float)CHUNK * ldr);
        float ph32 = (float)CHUNK * ldi;
        par[1024 + p] = e32 * cosf(ph32);       // PowR = Re(Lbar^32)
        par[1280 + p] = e32 * sinf(ph32);       // PowI
        par[1536 + p] = ldr;
        par[1792 + p] = ldi;
    } else if (b <= 1024) {
        int bb = b - 1;
        if (bb < 512) {
            int idx = bb * 256 + threadIdx.x;   // [0, P*H)
            int p = idx >> 9;                   // uniform per block
            float lr = fminf(Lre[p], -1e-4f);
            float li = Lim[p];
            float st = expf(lstep[p]);
            float er = expf(lr * st);
            float ar = er * cosf(li * st);
            float ai = er * sinf(li * st);
            float den = lr * lr + li * li;
            float mr = ar - 1.0f, mi = ai;
            float cr = (mr * lr + mi * li) / den;   // coef = (Lbar-1)/Lambda
            float ci = (mi * lr - mr * li) / den;
            float br = Bre[idx], bi = Bim[idx];
            int h = idx & 511;
            Bt[(size_t)p * NP2 + h]         = (__bf16)(cr * br - ci * bi);
            Bt[(size_t)(256 + p) * NP2 + h] = (__bf16)(cr * bi + ci * br);
        } else {
            int idx = (bb - 512) * 256 + threadIdx.x;   // [0, H*P)
            int h = idx >> 8;
            int q = idx & 255;
            Ct[(size_t)h * NP2 + q]       = (__bf16)( 2.0f * Cre[idx]);
            Ct[(size_t)h * NP2 + 256 + q] = (__bf16)(-2.0f * Cim[idx]);
        }
    } else {
        int i = (b - 1025) * 256 + threadIdx.x;     // [0, L*H/8)
        float4 a = uin[2 * i], c = uin[2 * i + 1];
        bf16x8 v;
        v[0] = (__bf16)a.x; v[1] = (__bf16)a.y; v[2] = (__bf16)a.z; v[3] = (__bf16)a.w;
        v[4] = (__bf16)c.x; v[5] = (__bf16)c.y; v[6] = (__bf16)c.z; v[7] = (__bf16)c.w;
        Ubf[i] = v;
    }
}

// ---------------- GEMM: A(M,512) bf16 x Bt(512,512) bf16 (N,K), 128x128 tile, BK=64 ----------------
// R8-validated core. A: 3 buffers (2 ahead); B: 2 buffers (1 ahead, L2-resident).
// Shared pool 80KB (2 blocks/CU), aliased by the epilogue staging (67.6KB).
// vmcnt ledger (4 loads/unit; per-iter issue B(t+1), A(t+2)): steady queue at
// wait = [A(t),B(t),A(t+1),B(t+1),A(t+2)] = 20 -> vmcnt(12) drains A(t)+B(t).
// ks=6 -> vmcnt(8); ks=7 -> vmcnt(0). Overwrites fenced by trailing barrier.
// Full 8-slot XOR source-side swizzle (rule #21) + swizzled reads (conflicts=0).
// Epilogue: stage acc f32 -> LDS (stride 132 = conflict-free pad), then each
// thread streams one 64-col row-half: float4 stores, bf16x8 Ubf, float4 Dvec.
// FUSE=false: out bf16 (Bu). FUSE=true: out f32 = acc + D[col]*Ubf[o].
template<bool FUSE>
__global__ __launch_bounds__(256)
void gemm_bt_kernel(const __bf16* __restrict__ A, const __bf16* __restrict__ Bt,
                    void* __restrict__ CoutV, const float* __restrict__ Dvec,
                    const __bf16* __restrict__ Ubf) {
    const int K = NP2, N = NP2;
    __shared__ __align__(16) char pool[81920];          // 48KB As[3] + 32KB Bs[2]
    __bf16* Asp = (__bf16*)pool;                        // 3 x 8192 elems
    __bf16* Bsp = (__bf16*)(pool + 49152);              // 2 x 8192 elems
    const int t = threadIdx.x;
    const int l = t & 63;
    const int w = t >> 6;
    const int wr = w >> 1, wc = w & 1;
    // XCD-aware bijective remap: 1024 blocks = 8 XCDs * 128 slots
    const int b    = blockIdx.x;
    const int n_sw = (b & 7) * 128 + (b >> 3);
    const int row0 = (n_sw >> 2) * 128;
    const int col0 = (n_sw & 3) * 128;
    const int lr = l & 15;
    const int lk = (l >> 4) * 8;
    f32x4 acc[4][4] = {};

    auto STAGE_A = [&](int buf, int k0) {
#pragma unroll
        for (int i = 0; i < 4; ++i) {
            int off = i * 256 + t;
            int r  = off >> 3;
            int ce = ((off & 7) ^ (r & 7)) * 8;
            gload_lds16(A + (size_t)(row0 + r) * K + (k0 + ce), Asp + buf * 8192 + off * 8);
        }
    };
    auto STAGE_B = [&](int buf, int k0) {
#pragma unroll
        for (int i = 0; i < 4; ++i) {
            int off = i * 256 + t;
            int r  = off >> 3;
            int ce = ((off & 7) ^ (r & 7)) * 8;
            gload_lds16(Bt + (size_t)(col0 + r) * K + (k0 + ce), Bsp + buf * 8192 + off * 8);
        }
    };

    auto COMPUTE = [&](int ba, int bb) {
#pragma unroll
        for (int kk = 0; kk < 64; kk += 32) {
            bf16x8 a[4], b2[4];
            const int ls = (kk + lk) >> 3;
#pragma unroll
            for (int m = 0; m < 4; ++m) {
                int row = wr * 64 + m * 16 + lr;
                a[m] = *reinterpret_cast<const bf16x8*>(Asp + ba * 8192 + row * 64 + ((ls ^ (row & 7)) << 3));
            }
#pragma unroll
            for (int n = 0; n < 4; ++n) {
                int row = wc * 64 + n * 16 + lr;
                b2[n] = *reinterpret_cast<const bf16x8*>(Bsp + bb * 8192 + row * 64 + ((ls ^ (row & 7)) << 3));
            }
            __builtin_amdgcn_s_setprio(1);
#pragma unroll
            for (int m = 0; m < 4; ++m)
#pragma unroll
                for (int n = 0; n < 4; ++n)
                    acc[m][n] = __builtin_amdgcn_mfma_f32_16x16x32_bf16(a[m], b2[n], acc[m][n], 0, 0, 0);
            __builtin_amdgcn_s_setprio(0);
        }
    };

    // prologue: A0, B0, A1  (queue = 12)
    STAGE_A(0, 0);
    STAGE_B(0, 0);
    STAGE_A(1, 64);
#pragma unroll
    for (int ks = 0; ks < 8; ++ks) {
        if (ks + 1 < 8) STAGE_B((ks + 1) & 1, (ks + 1) * 64);
        if (ks + 2 < 8) STAGE_A((ks + 2) % 3, (ks + 2) * 64);
        if (ks <= 5)      { asm volatile("s_waitcnt vmcnt(12)" ::: "memory"); }
        else if (ks == 6) { asm volatile("s_waitcnt vmcnt(8)"  ::: "memory"); }
        else              { asm volatile("s_waitcnt vmcnt(0)"  ::: "memory"); }
        __builtin_amdgcn_s_barrier();           // A(ks),B(ks) staged by ALL waves
        __builtin_amdgcn_sched_barrier(0);
        COMPUTE(ks % 3, ks & 1);
        __builtin_amdgcn_sched_barrier(0);
        __builtin_amdgcn_s_barrier();           // all waves done reading bufs of tile ks
    }

    // ---- epilogue: LDS-staged coalesced writes (aliases As/Bs; safe after
    // the trailing barrier above) ----
    float* st = (float*)pool;                   // 128 rows x stride 132 f32
    const int lg = (l >> 4) * 4;
#pragma unroll
    for (int m = 0; m < 4; ++m)
#pragma unroll
        for (int n = 0; n < 4; ++n)
#pragma unroll
            for (int j = 0; j < 4; ++j)
                st[(wr * 64 + m * 16 + lg + j) * 132 + (wc * 64 + n * 16 + lr)] = acc[m][n][j];
    __syncthreads();

    const int row  = t >> 1;
    const int half = t & 1;
    const float* srow = st + row * 132 + half * 64;
    const size_t gbase = (size_t)(row0 + row) * N + col0 + half * 64;
    if (FUSE) {
        float* out = (float*)CoutV;
        const float* dv = Dvec + col0 + half * 64;
#pragma unroll
        for (int c = 0; c < 8; ++c) {
            float4 v0 = *(const float4*)(srow + c * 8);
            float4 v1 = *(const float4*)(srow + c * 8 + 4);
            bf16x8 uv = *reinterpret_cast<const bf16x8*>(Ubf + gbase + c * 8);
            float4 d0 = *(const float4*)(dv + c * 8);
            float4 d1 = *(const float4*)(dv + c * 8 + 4);
            float4 o0, o1;
            o0.x = fmaf(d0.x, (float)uv[0], v0.x);
            o0.y = fmaf(d0.y, (float)uv[1], v0.y);
            o0.z = fmaf(d0.z, (float)uv[2], v0.z);
            o0.w = fmaf(d0.w, (float)uv[3], v0.w);
            o1.x = fmaf(d1.x, (float)uv[4], v1.x);
            o1.y = fmaf(d1.y, (float)uv[5], v1.y);
            o1.z = fmaf(d1.z, (float)uv[6], v1.z);
            o1.w = fmaf(d1.w, (float)uv[7], v1.w);
            *(float4*)(out + gbase + c * 8)     = o0;
            *(float4*)(out + gbase + c * 8 + 4) = o1;
        }
    } else {
        __bf16* out = (__bf16*)CoutV;
#pragma unroll
        for (int c = 0; c < 8; ++c) {
            float4 v0 = *(const float4*)(srow + c * 8);
            float4 v1 = *(const float4*)(srow + c * 8 + 4);
            bf16x8 v;
            v[0] = (__bf16)v0.x; v[1] = (__bf16)v0.y; v[2] = (__bf16)v0.z; v[3] = (__bf16)v0.w;
            v[4] = (__bf16)v1.x; v[5] = (__bf16)v1.y; v[6] = (__bf16)v1.z; v[7] = (__bf16)v1.w;
            *reinterpret_cast<bf16x8*>(out + gbase + c * 8) = v;
        }
    }
}

// ---------------- chunked scan (Bu bf16; 128 threads, 2 channels/thread) ----------------
// Level 0: per-chunk totals. Fc[g*128+t] = (xr0, xi0, xr1, xi1) for channels 2t, 2t+1.
__global__ void scanA_kernel(const __bf16* __restrict__ Bu, const float* __restrict__ par,
                             float4* __restrict__ Fc) {
    int g = blockIdx.x;
    int t = threadIdx.x;                // 0..127
    int p0 = 2 * t;
    float ar0 = par[p0], ai0 = par[256 + p0];
    float ar1 = par[p0 + 1], ai1 = par[256 + p0 + 1];
    const __bf16* bu = Bu + (size_t)g * CHUNK * NP2;
    float xr0 = 0.f, xi0 = 0.f, xr1 = 0.f, xi1 = 0.f;
#pragma unroll 4
    for (int i = 0; i < CHUNK; ++i) {
        bf16x2 re = *reinterpret_cast<const bf16x2*>(bu + i * NP2 + p0);
        bf16x2 im = *reinterpret_cast<const bf16x2*>(bu + i * NP2 + 256 + p0);
        float nr0 = fmaf(ar0, xr0, fmaf(-ai0, xi0, (float)re[0]));
        float ni0 = fmaf(ar0, xi0, fmaf( ai0, xr0, (float)im[0]));
        float nr1 = fmaf(ar1, xr1, fmaf(-ai1, xi1, (float)re[1]));
        float ni1 = fmaf(ar1, xi1, fmaf( ai1, xr1, (float)im[1]));
        xr0 = nr0; xi0 = ni0; xr1 = nr1; xi1 = ni1;
    }
    float4 f; f.x = xr0; f.y = xi0; f.z = xr1; f.w = xi1;
    Fc[g * 128 + t] = f;
}

// Level 1: 32 blocks; block s scans its 32 chunks with Lbar^32. Writes
// within-super exclusive prefixes Lc[g] and super totals Tc[s]. (Restored —
// R11's single serial chain was latency-bound: 626cy/iter x 1023 = 267us.)
__global__ void scanB1_kernel(const float4* __restrict__ Fc, const float* __restrict__ par,
                              float4* __restrict__ Lc, float4* __restrict__ Tc) {
    int s = blockIdx.x;
    int t = threadIdx.x;                // 0..127
    int p0 = 2 * t;
    float pr0 = par[1024 + p0], pi0 = par[1280 + p0];
    float pr1 = par[1024 + p0 + 1], pi1 = par[1280 + p0 + 1];
    float er0 = 0.f, ei0 = 0.f, er1 = 0.f, ei1 = 0.f;
    int base = s * 32;
#pragma unroll
    for (int j = 0; j < 32; ++j) {
        float4 e; e.x = er0; e.y = ei0; e.z = er1; e.w = ei1;
        Lc[(base + j) * 128 + t] = e;
        float4 f = Fc[(base + j) * 128 + t];
        float nr0 = fmaf(pr0, er0, fmaf(-pi0, ei0, f.x));
        float ni0 = fmaf(pr0, ei0, fmaf( pi0, er0, f.y));
        float nr1 = fmaf(pr1, er1, fmaf(-pi1, ei1, f.z));
        float ni1 = fmaf(pr1, ei1, fmaf( pi1, er1, f.w));
        er0 = nr0; ei0 = ni0; er1 = nr1; ei1 = ni1;
    }
    float4 tt; tt.x = er0; tt.y = ei0; tt.z = er1; tt.w = ei1;
    Tc[s * 128 + t] = tt;
}

// Final: E[s] = exclusive scan over super totals (<=31 iters, Lbar^1024);
// carry = Lbar^(32k) * E[s] + Lc[g]; 32-row replay writes xs (bf16).
__global__ void scanC_kernel(const __bf16* __restrict__ Bu, const float* __restrict__ par,
                             const float4* __restrict__ Lc, const float4* __restrict__ Tc,
                             __bf16* __restrict__ xs) {
    int g = blockIdx.x;
    int t = threadIdx.x;                // 0..127
    int s = g >> 5, k = g & 31;
    int p0 = 2 * t;
    float ar0 = par[p0], ai0 = par[256 + p0];
    float ar1 = par[p0 + 1], ai1 = par[256 + p0 + 1];
    float ldr0 = par[1536 + p0], ldi0 = par[1792 + p0];
    float ldr1 = par[1536 + p0 + 1], ldi1 = par[1792 + p0 + 1];
    // Lbar^1024 per channel
    float e10 = expf(1024.0f * ldr0), ph10 = 1024.0f * ldi0;
    float q1r0 = e10 * cosf(ph10), q1i0 = e10 * sinf(ph10);
    float e11 = expf(1024.0f * ldr1), ph11 = 1024.0f * ldi1;
    float q1r1 = e11 * cosf(ph11), q1i1 = e11 * sinf(ph11);
    // E[s]: exclusive scan over super totals
    float er0 = 0.f, ei0 = 0.f, er1 = 0.f, ei1 = 0.f;
    for (int s2 = 0; s2 < s; ++s2) {
        float4 f = Tc[s2 * 128 + t];
        float nr0 = fmaf(q1r0, er0, fmaf(-q1i0, ei0, f.x));
        float ni0 = fmaf(q1r0, ei0, fmaf( q1i0, er0, f.y));
        float nr1 = fmaf(q1r1, er1, fmaf(-q1i1, ei1, f.z));
        float ni1 = fmaf(q1r1, ei1, fmaf( q1i1, er1, f.w));
        er0 = nr0; ei0 = ni0; er1 = nr1; ei1 = ni1;
    }
    // Lbar^(32k) per channel
    float kk = (float)(32 * k);
    float ek0 = expf(kk * ldr0), phk0 = kk * ldi0;
    float qr0 = ek0 * cosf(phk0), qi0 = ek0 * sinf(phk0);
    float ek1 = expf(kk * ldr1), phk1 = kk * ldi1;
    float qr1 = ek1 * cosf(phk1), qi1 = ek1 * sinf(phk1);
    float4 l0 = Lc[g * 128 + t];
    float xr0 = fmaf(qr0, er0, fmaf(-qi0, ei0, l0.x));
    float xi0 = fmaf(qr0, ei0, fmaf( qi0, er0, l0.y));
    float xr1 = fmaf(qr1, er1, fmaf(-qi1, ei1, l0.z));
    float xi1 = fmaf(qr1, ei1, fmaf( qi1, er1, l0.w));
    const __bf16* bu = Bu + (size_t)g * CHUNK * NP2;
    __bf16* xo = xs + (size_t)g * CHUNK * NP2;
#pragma unroll 4
    for (int i = 0; i < CHUNK; ++i) {
        bf16x2 re = *reinterpret_cast<const bf16x2*>(bu + i * NP2 + p0);
        bf16x2 im = *reinterpret_cast<const bf16x2*>(bu + i * NP2 + 256 + p0);
        float nr0 = fmaf(ar0, xr0, fmaf(-ai0, xi0, (float)re[0]));
        float ni0 = fmaf(ar0, xi0, fmaf( ai0, xr0, (float)im[0]));
        float nr1 = fmaf(ar1, xr1, fmaf(-ai1, xi1, (float)re[1]));
        float ni1 = fmaf(ar1, xi1, fmaf( ai1, xr1, (float)im[1]));
        xr0 = nr0; xi0 = ni0; xr1 = nr1; xi1 = ni1;
        bf16x2 wre; wre[0] = (__bf16)xr0; wre[1] = (__bf16)xr1;
        bf16x2 wim; wim[0] = (__bf16)xi0; wim[1] = (__bf16)xi1;
        *reinterpret_cast<bf16x2*>(xo + i * NP2 + p0)       = wre;
        *reinterpret_cast<bf16x2*>(xo + i * NP2 + 256 + p0) = wim;
    }
}

extern "C" void kernel_launch(void* const* d_in, const int* in_sizes, int n_in,
                              void* d_out, int out_size, void* d_ws, size_t ws_size,
                              hipStream_t stream) {
    const float* u   = (const float*)d_in[0];
    const float* Lre = (const float*)d_in[1];
    const float* Lim = (const float*)d_in[2];
    const float* Bre = (const float*)d_in[3];
    const float* Bim = (const float*)d_in[4];
    const float* Cre = (const float*)d_in[5];
    const float* Cim = (const float*)d_in[6];
    const float* Dv  = (const float*)d_in[7];
    const float* lst = (const float*)d_in[8];

    char* w = (char*)d_ws;
    size_t off = 0;
    float* par = (float*)(w + off);      off += 16 * 1024;
    __bf16* Btm = (__bf16*)(w + off);    off += (size_t)NP2 * NP2 * 2;      // 512 KB
    __bf16* Ctm = (__bf16*)(w + off);    off += (size_t)NP2 * NP2 * 2;      // 512 KB
    float4* Fc = (float4*)(w + off);     off += (size_t)NCHUNK * 128 * 16;  // 2 MB
    float4* Lc = (float4*)(w + off);     off += (size_t)NCHUNK * 128 * 16;  // 2 MB
    float4* Tc = (float4*)(w + off);     off += (size_t)NSUPER * 128 * 16;  // 64 KB
    __bf16* Ubf = (__bf16*)(w + off);    off += (size_t)L_SEQ * H_DIM * 2;  // 32 MB (bf16 u)
    __bf16* Xs  = (__bf16*)(w + off);    off += (size_t)L_SEQ * NP2 * 2;    // 32 MB (xs)
    if (ws_size < off) return;  // fail loudly (output stays poisoned)

    // Bu: bf16 L x 2P (32 MB) in the lower half of d_out; GEMM2 overwrites
    // all of d_out (f32 output) afterwards.
    __bf16* Bu = (__bf16*)d_out;

    setup_kernel  <<<9217, 256, 0, stream>>>(Lre, Lim, lst, Bre, Bim, Cre, Cim,
                                             (const float4*)u, par, Btm, Ctm, (bf16x8*)Ubf);
    gemm_bt_kernel<false><<<1024, 256, 0, stream>>>(Ubf, Btm, (void*)Bu, nullptr, nullptr);
    scanA_kernel  <<<NCHUNK, 128, 0, stream>>>(Bu, par, Fc);
    scanB1_kernel <<<NSUPER, 128, 0, stream>>>(Fc, par, Lc, Tc);
    scanC_kernel  <<<NCHUNK, 128, 0, stream>>>(Bu, par, Lc, Tc, Xs);
    gemm_bt_kernel<true><<<1024, 256, 0, stream>>>(Xs, Ctm, d_out, Dv, Ubf);
}

// Round 13
// 98.313 us; speedup vs baseline: 3.7160x; 1.2448x over previous
//
#include <hip/hip_runtime.h>
#include <cstdint>
#include <cstddef>

typedef __bf16 bf16x8 __attribute__((ext_vector_type(8)));
typedef __bf16 bf16x2 __attribute__((ext_vector_type(2)));
typedef float f32x4 __attribute__((ext_vector_type(4)));

#define L_SEQ 32768
#define H_DIM 512
#define P_DIM 256
#define NP2   512      // 2P = K and N of both GEMMs
#define CHUNK 32
#define NCHUNK 1024    // L / CHUNK
#define NSUPER 32      // NCHUNK / 32

__device__ __forceinline__ void gload_lds16(const void* g, void* l) {
    __builtin_amdgcn_global_load_lds(
        (const __attribute__((address_space(1))) void*)g,
        (__attribute__((address_space(3))) void*)l,
        16, 0, 0);
}

// ---------------- fused setup: prep (block 0) | build B/C (blocks 1..1024) |
// cast u->bf16 (blocks 1025..9216). Builders recompute coef inline (p uniform
// per block -> scalar transcendentals, free).
// par layout (floats): [0]=Ar [256]=Ai [1024]=PowR(Lbar^32) [1280]=PowI
//                      [1536]=ldr [1792]=ldi
__global__ void setup_kernel(const float* __restrict__ Lre, const float* __restrict__ Lim,
                             const float* __restrict__ lstep,
                             const float* __restrict__ Bre, const float* __restrict__ Bim,
                             const float* __restrict__ Cre, const float* __restrict__ Cim,
                             const float4* __restrict__ uin,
                             float* __restrict__ par,
                             __bf16* __restrict__ Bt, __bf16* __restrict__ Ct,
                             bf16x8* __restrict__ Ubf) {
    int b = blockIdx.x;
    if (b == 0) {
        int p = threadIdx.x;
        float lr = fminf(Lre[p], -1e-4f);       // clip_eigs
        float li = Lim[p];
        float st = expf(lstep[p]);
        float ldr = lr * st;
        float ldi = li * st;
        float er = expf(ldr);
        par[p]        = er * cosf(ldi);         // Ar
        par[256 + p]  = er * sinf(ldi);         // Ai
        float e32  = expf((float)CHUNK * ldr);
        float ph32 = (float)CHUNK * ldi;
        par[1024 + p] = e32 * cosf(ph32);       // PowR = Re(Lbar^32)
        par[1280 + p] = e32 * sinf(ph32);       // PowI
        par[1536 + p] = ldr;
        par[1792 + p] = ldi;
    } else if (b <= 1024) {
        int bb = b - 1;
        if (bb < 512) {
            int idx = bb * 256 + threadIdx.x;   // [0, P*H)
            int p = idx >> 9;                   // uniform per block
            float lr = fminf(Lre[p], -1e-4f);
            float li = Lim[p];
            float st = expf(lstep[p]);
            float er = expf(lr * st);
            float ar = er * cosf(li * st);
            float ai = er * sinf(li * st);
            float den = lr * lr + li * li;
            float mr = ar - 1.0f, mi = ai;
            float cr = (mr * lr + mi * li) / den;   // coef = (Lbar-1)/Lambda
            float ci = (mi * lr - mr * li) / den;
            float br = Bre[idx], bi = Bim[idx];
            int h = idx & 511;
            Bt[(size_t)p * NP2 + h]         = (__bf16)(cr * br - ci * bi);
            Bt[(size_t)(256 + p) * NP2 + h] = (__bf16)(cr * bi + ci * br);
        } else {
            int idx = (bb - 512) * 256 + threadIdx.x;   // [0, H*P)
            int h = idx >> 8;
            int q = idx & 255;
            Ct[(size_t)h * NP2 + q]       = (__bf16)( 2.0f * Cre[idx]);
            Ct[(size_t)h * NP2 + 256 + q] = (__bf16)(-2.0f * Cim[idx]);
        }
    } else {
        int i = (b - 1025) * 256 + threadIdx.x;     // [0, L*H/8)
        float4 a = uin[2 * i], c = uin[2 * i + 1];
        bf16x8 v;
        v[0] = (__bf16)a.x; v[1] = (__bf16)a.y; v[2] = (__bf16)a.z; v[3] = (__bf16)a.w;
        v[4] = (__bf16)c.x; v[5] = (__bf16)c.y; v[6] = (__bf16)c.z; v[7] = (__bf16)c.w;
        Ubf[i] = v;
    }
}

// ---------------- GEMM: A(M,512) bf16 x Bt(512,512) bf16 (N,K), 128x128 tile, BK=64 ----------------
// EXACT R8/R10 config (the 98.2us-total version). Direct-store epilogue —
// R12's LDS-staged epilogue put adjacent lanes 1KB apart (64 transactions per
// store instr, WRITE_SIZE 66MB vs 32MB) and cost ~+19us/GEMM. The direct
// pattern (16 lanes = 32B-contiguous runs) merges fine: WRITE_SIZE = 32MB.
// A: 3 buffers (2 ahead); B: 2 buffers (1 ahead, L2-resident). LDS 80KB.
// vmcnt ledger (4 loads/unit; per-iter issue B(t+1), A(t+2)): steady queue at
// wait = [A(t),B(t),A(t+1),B(t+1),A(t+2)] = 20 -> vmcnt(12) drains A(t)+B(t).
// ks=6 -> vmcnt(8); ks=7 -> vmcnt(0). Overwrites fenced by trailing barrier.
// Full 8-slot XOR source-side swizzle (rule #21) + swizzled reads (conflicts=0).
// FUSE=false: out bf16 (Bu). FUSE=true: out f32 = acc + D[col]*Ubf[o].
template<bool FUSE>
__global__ __launch_bounds__(256)
void gemm_bt_kernel(const __bf16* __restrict__ A, const __bf16* __restrict__ Bt,
                    void* __restrict__ CoutV, const float* __restrict__ Dvec,
                    const __bf16* __restrict__ Ubf) {
    const int K = NP2, N = NP2;
    __shared__ __align__(16) __bf16 As[3][128 * 64];
    __shared__ __align__(16) __bf16 Bs[2][128 * 64];
    const int t = threadIdx.x;
    const int l = t & 63;
    const int w = t >> 6;
    const int wr = w >> 1, wc = w & 1;
    // XCD-aware bijective remap: 1024 blocks = 8 XCDs * 128 slots
    const int b    = blockIdx.x;
    const int n_sw = (b & 7) * 128 + (b >> 3);
    const int row0 = (n_sw >> 2) * 128;
    const int col0 = (n_sw & 3) * 128;
    const int lr = l & 15;
    const int lk = (l >> 4) * 8;
    f32x4 acc[4][4] = {};

    auto STAGE_A = [&](int buf, int k0) {
#pragma unroll
        for (int i = 0; i < 4; ++i) {
            int off = i * 256 + t;
            int r  = off >> 3;
            int ce = ((off & 7) ^ (r & 7)) * 8;
            gload_lds16(A + (size_t)(row0 + r) * K + (k0 + ce), &As[buf][off * 8]);
        }
    };
    auto STAGE_B = [&](int buf, int k0) {
#pragma unroll
        for (int i = 0; i < 4; ++i) {
            int off = i * 256 + t;
            int r  = off >> 3;
            int ce = ((off & 7) ^ (r & 7)) * 8;
            gload_lds16(Bt + (size_t)(col0 + r) * K + (k0 + ce), &Bs[buf][off * 8]);
        }
    };

    auto COMPUTE = [&](int ba, int bb) {
#pragma unroll
        for (int kk = 0; kk < 64; kk += 32) {
            bf16x8 a[4], b2[4];
            const int ls = (kk + lk) >> 3;
#pragma unroll
            for (int m = 0; m < 4; ++m) {
                int row = wr * 64 + m * 16 + lr;
                a[m] = *reinterpret_cast<const bf16x8*>(&As[ba][row * 64 + ((ls ^ (row & 7)) << 3)]);
            }
#pragma unroll
            for (int n = 0; n < 4; ++n) {
                int row = wc * 64 + n * 16 + lr;
                b2[n] = *reinterpret_cast<const bf16x8*>(&Bs[bb][row * 64 + ((ls ^ (row & 7)) << 3)]);
            }
            __builtin_amdgcn_s_setprio(1);
#pragma unroll
            for (int m = 0; m < 4; ++m)
#pragma unroll
                for (int n = 0; n < 4; ++n)
                    acc[m][n] = __builtin_amdgcn_mfma_f32_16x16x32_bf16(a[m], b2[n], acc[m][n], 0, 0, 0);
            __builtin_amdgcn_s_setprio(0);
        }
    };

    // prologue: A0, B0, A1  (queue = 12)
    STAGE_A(0, 0);
    STAGE_B(0, 0);
    STAGE_A(1, 64);
#pragma unroll
    for (int ks = 0; ks < 8; ++ks) {
        if (ks + 1 < 8) STAGE_B((ks + 1) & 1, (ks + 1) * 64);
        if (ks + 2 < 8) STAGE_A((ks + 2) % 3, (ks + 2) * 64);
        if (ks <= 5)      { asm volatile("s_waitcnt vmcnt(12)" ::: "memory"); }
        else if (ks == 6) { asm volatile("s_waitcnt vmcnt(8)"  ::: "memory"); }
        else              { asm volatile("s_waitcnt vmcnt(0)"  ::: "memory"); }
        __builtin_amdgcn_s_barrier();           // A(ks),B(ks) staged by ALL waves
        __builtin_amdgcn_sched_barrier(0);
        COMPUTE(ks % 3, ks & 1);
        __builtin_amdgcn_sched_barrier(0);
        __builtin_amdgcn_s_barrier();           // all waves done reading bufs of tile ks
    }

    const int lg = (l >> 4) * 4;
#pragma unroll
    for (int m = 0; m < 4; ++m) {
#pragma unroll
        for (int n = 0; n < 4; ++n) {
            int col = col0 + wc * 64 + n * 16 + lr;
#pragma unroll
            for (int j = 0; j < 4; ++j) {
                int row = row0 + wr * 64 + m * 16 + lg + j;
                size_t o = (size_t)row * N + col;
                if (FUSE) {
                    ((float*)CoutV)[o] = acc[m][n][j] + Dvec[col] * (float)Ubf[o];
                } else {
                    ((__bf16*)CoutV)[o] = (__bf16)acc[m][n][j];
                }
            }
        }
    }
}

// ---------------- chunked scan (Bu bf16; 128 threads, 2 channels/thread) ----------------
// Level 0: per-chunk totals. Fc[g*128+t] = (xr0, xi0, xr1, xi1) for channels 2t, 2t+1.
__global__ void scanA_kernel(const __bf16* __restrict__ Bu, const float* __restrict__ par,
                             float4* __restrict__ Fc) {
    int g = blockIdx.x;
    int t = threadIdx.x;                // 0..127
    int p0 = 2 * t;
    float ar0 = par[p0], ai0 = par[256 + p0];
    float ar1 = par[p0 + 1], ai1 = par[256 + p0 + 1];
    const __bf16* bu = Bu + (size_t)g * CHUNK * NP2;
    float xr0 = 0.f, xi0 = 0.f, xr1 = 0.f, xi1 = 0.f;
#pragma unroll 4
    for (int i = 0; i < CHUNK; ++i) {
        bf16x2 re = *reinterpret_cast<const bf16x2*>(bu + i * NP2 + p0);
        bf16x2 im = *reinterpret_cast<const bf16x2*>(bu + i * NP2 + 256 + p0);
        float nr0 = fmaf(ar0, xr0, fmaf(-ai0, xi0, (float)re[0]));
        float ni0 = fmaf(ar0, xi0, fmaf( ai0, xr0, (float)im[0]));
        float nr1 = fmaf(ar1, xr1, fmaf(-ai1, xi1, (float)re[1]));
        float ni1 = fmaf(ar1, xi1, fmaf( ai1, xr1, (float)im[1]));
        xr0 = nr0; xi0 = ni0; xr1 = nr1; xi1 = ni1;
    }
    float4 f; f.x = xr0; f.y = xi0; f.z = xr1; f.w = xi1;
    Fc[g * 128 + t] = f;
}

// Level 1: 32 blocks; block s scans its 32 chunks with Lbar^32. Writes
// within-super exclusive prefixes Lc[g] and super totals Tc[s].
__global__ void scanB1_kernel(const float4* __restrict__ Fc, const float* __restrict__ par,
                              float4* __restrict__ Lc, float4* __restrict__ Tc) {
    int s = blockIdx.x;
    int t = threadIdx.x;                // 0..127
    int p0 = 2 * t;
    float pr0 = par[1024 + p0], pi0 = par[1280 + p0];
    float pr1 = par[1024 + p0 + 1], pi1 = par[1280 + p0 + 1];
    float er0 = 0.f, ei0 = 0.f, er1 = 0.f, ei1 = 0.f;
    int base = s * 32;
#pragma unroll
    for (int j = 0; j < 32; ++j) {
        float4 e; e.x = er0; e.y = ei0; e.z = er1; e.w = ei1;
        Lc[(base + j) * 128 + t] = e;
        float4 f = Fc[(base + j) * 128 + t];
        float nr0 = fmaf(pr0, er0, fmaf(-pi0, ei0, f.x));
        float ni0 = fmaf(pr0, ei0, fmaf( pi0, er0, f.y));
        float nr1 = fmaf(pr1, er1, fmaf(-pi1, ei1, f.z));
        float ni1 = fmaf(pr1, ei1, fmaf( pi1, er1, f.w));
        er0 = nr0; ei0 = ni0; er1 = nr1; ei1 = ni1;
    }
    float4 tt; tt.x = er0; tt.y = ei0; tt.z = er1; tt.w = ei1;
    Tc[s * 128 + t] = tt;
}

// Final: E[s] = exclusive scan over super totals (<=31 iters, Lbar^1024);
// carry = Lbar^(32k) * E[s] + Lc[g]; 32-row replay writes xs (bf16).
__global__ void scanC_kernel(const __bf16* __restrict__ Bu, const float* __restrict__ par,
                             const float4* __restrict__ Lc, const float4* __restrict__ Tc,
                             __bf16* __restrict__ xs) {
    int g = blockIdx.x;
    int t = threadIdx.x;                // 0..127
    int s = g >> 5, k = g & 31;
    int p0 = 2 * t;
    float ar0 = par[p0], ai0 = par[256 + p0];
    float ar1 = par[p0 + 1], ai1 = par[256 + p0 + 1];
    float ldr0 = par[1536 + p0], ldi0 = par[1792 + p0];
    float ldr1 = par[1536 + p0 + 1], ldi1 = par[1792 + p0 + 1];
    // Lbar^1024 per channel
    float e10 = expf(1024.0f * ldr0), ph10 = 1024.0f * ldi0;
    float q1r0 = e10 * cosf(ph10), q1i0 = e10 * sinf(ph10);
    float e11 = expf(1024.0f * ldr1), ph11 = 1024.0f * ldi1;
    float q1r1 = e11 * cosf(ph11), q1i1 = e11 * sinf(ph11);
    // E[s]: exclusive scan over super totals
    float er0 = 0.f, ei0 = 0.f, er1 = 0.f, ei1 = 0.f;
    for (int s2 = 0; s2 < s; ++s2) {
        float4 f = Tc[s2 * 128 + t];
        float nr0 = fmaf(q1r0, er0, fmaf(-q1i0, ei0, f.x));
        float ni0 = fmaf(q1r0, ei0, fmaf( q1i0, er0, f.y));
        float nr1 = fmaf(q1r1, er1, fmaf(-q1i1, ei1, f.z));
        float ni1 = fmaf(q1r1, ei1, fmaf( q1i1, er1, f.w));
        er0 = nr0; ei0 = ni0; er1 = nr1; ei1 = ni1;
    }
    // Lbar^(32k) per channel
    float kk = (float)(32 * k);
    float ek0 = expf(kk * ldr0), phk0 = kk * ldi0;
    float qr0 = ek0 * cosf(phk0), qi0 = ek0 * sinf(phk0);
    float ek1 = expf(kk * ldr1), phk1 = kk * ldi1;
    float qr1 = ek1 * cosf(phk1), qi1 = ek1 * sinf(phk1);
    float4 l0 = Lc[g * 128 + t];
    float xr0 = fmaf(qr0, er0, fmaf(-qi0, ei0, l0.x));
    float xi0 = fmaf(qr0, ei0, fmaf( qi0, er0, l0.y));
    float xr1 = fmaf(qr1, er1, fmaf(-qi1, ei1, l0.z));
    float xi1 = fmaf(qr1, ei1, fmaf( qi1, er1, l0.w));
    const __bf16* bu = Bu + (size_t)g * CHUNK * NP2;
    __bf16* xo = xs + (size_t)g * CHUNK * NP2;
#pragma unroll 4
    for (int i = 0; i < CHUNK; ++i) {
        bf16x2 re = *reinterpret_cast<const bf16x2*>(bu + i * NP2 + p0);
        bf16x2 im = *reinterpret_cast<const bf16x2*>(bu + i * NP2 + 256 + p0);
        float nr0 = fmaf(ar0, xr0, fmaf(-ai0, xi0, (float)re[0]));
        float ni0 = fmaf(ar0, xi0, fmaf( ai0, xr0, (float)im[0]));
        float nr1 = fmaf(ar1, xr1, fmaf(-ai1, xi1, (float)re[1]));
        float ni1 = fmaf(ar1, xi1, fmaf( ai1, xr1, (float)im[1]));
        xr0 = nr0; xi0 = ni0; xr1 = nr1; xi1 = ni1;
        bf16x2 wre; wre[0] = (__bf16)xr0; wre[1] = (__bf16)xr1;
        bf16x2 wim; wim[0] = (__bf16)xi0; wim[1] = (__bf16)xi1;
        *reinterpret_cast<bf16x2*>(xo + i * NP2 + p0)       = wre;
        *reinterpret_cast<bf16x2*>(xo + i * NP2 + 256 + p0) = wim;
    }
}

extern "C" void kernel_launch(void* const* d_in, const int* in_sizes, int n_in,
                              void* d_out, int out_size, void* d_ws, size_t ws_size,
                              hipStream_t stream) {
    const float* u   = (const float*)d_in[0];
    const float* Lre = (const float*)d_in[1];
    const float* Lim = (const float*)d_in[2];
    const float* Bre = (const float*)d_in[3];
    const float* Bim = (const float*)d_in[4];
    const float* Cre = (const float*)d_in[5];
    const float* Cim = (const float*)d_in[6];
    const float* Dv  = (const float*)d_in[7];
    const float* lst = (const float*)d_in[8];

    char* w = (char*)d_ws;
    size_t off = 0;
    float* par = (float*)(w + off);      off += 16 * 1024;
    __bf16* Btm = (__bf16*)(w + off);    off += (size_t)NP2 * NP2 * 2;      // 512 KB
    __bf16* Ctm = (__bf16*)(w + off);    off += (size_t)NP2 * NP2 * 2;      // 512 KB
    float4* Fc = (float4*)(w + off);     off += (size_t)NCHUNK * 128 * 16;  // 2 MB
    float4* Lc = (float4*)(w + off);     off += (size_t)NCHUNK * 128 * 16;  // 2 MB
    float4* Tc = (float4*)(w + off);     off += (size_t)NSUPER * 128 * 16;  // 64 KB
    __bf16* Ubf = (__bf16*)(w + off);    off += (size_t)L_SEQ * H_DIM * 2;  // 32 MB (bf16 u)
    __bf16* Xs  = (__bf16*)(w + off);    off += (size_t)L_SEQ * NP2 * 2;    // 32 MB (xs)
    if (ws_size < off) return;  // fail loudly (output stays poisoned)

    // Bu: bf16 L x 2P (32 MB) in the lower half of d_out; GEMM2 overwrites
    // all of d_out (f32 output) afterwards.
    __bf16* Bu = (__bf16*)d_out;

    setup_kernel  <<<9217, 256, 0, stream>>>(Lre, Lim, lst, Bre, Bim, Cre, Cim,
                                             (const float4*)u, par, Btm, Ctm, (bf16x8*)Ubf);
    gemm_bt_kernel<false><<<1024, 256, 0, stream>>>(Ubf, Btm, (void*)Bu, nullptr, nullptr);
    scanA_kernel  <<<NCHUNK, 128, 0, stream>>>(Bu, par, Fc);
    scanB1_kernel <<<NSUPER, 128, 0, stream>>>(Fc, par, Lc, Tc);
    scanC_kernel  <<<NCHUNK, 128, 0, stream>>>(Bu, par, Lc, Tc, Xs);
    gemm_bt_kernel<true><<<1024, 256, 0, stream>>>(Xs, Ctm, d_out, Dv, Ubf);
}